// Round 1
// baseline (505.684 us; speedup 1.0000x reference)
//
#include <hip/hip_runtime.h>

typedef _Float16 half_t;
typedef _Float16 half8  __attribute__((ext_vector_type(8)));
typedef _Float16 half4v __attribute__((ext_vector_type(4)));
typedef float    f32x4  __attribute__((ext_vector_type(4)));

#define ROWB   528          // 64x256 f16 tile, padded row stride (bytes): 2-way banks max
#define VROWB  144          // sVt 256x64 f16 tile row stride (bytes)
#define S_X    0            // x staging -> later K (token-major) + P[j>=32]
#define S_Y    33792        // y staging
#define S_Q    67584        // Q -> P[j<32] -> O (token-major)
#define S_VT   101376       // V transposed [feature][token]
#define SMEM_BYTES 138240
#define SCALE  0.17677669529663687f

// ---- prep: weights f32->f16 into ws, expand rel-pos bias to [8][64][64] f32
__global__ __launch_bounds__(256) void swin_prep(
    const float* __restrict__ q_w, const float* __restrict__ kv_w,
    const float* __restrict__ proj_w, const float* __restrict__ rpb,
    half_t* __restrict__ w16, float* __restrict__ bias_exp)
{
    int t = blockIdx.x * 256 + threadIdx.x;
    if (t < 65536)        w16[t] = (half_t)q_w[t];
    else if (t < 196608)  w16[t] = (half_t)kv_w[t - 65536];
    else if (t < 262144)  w16[t] = (half_t)proj_w[t - 196608];
    else {
        int u = t - 262144;                 // [0, 32768)
        int h = u >> 12, rest = u & 4095, i = rest >> 6, j = rest & 63;
        int idx = ((i >> 3) - (j >> 3) + 7) * 15 + ((i & 7) - (j & 7) + 7);
        bias_exp[u] = rpb[idx * 8 + h];
    }
}

__global__ __launch_bounds__(512) void swin_main(
    const float* __restrict__ x, const float* __restrict__ y,
    const float* __restrict__ mask,
    const float* __restrict__ q_b, const float* __restrict__ kv_b,
    const float* __restrict__ proj_b,
    const half_t* __restrict__ w16, const float* __restrict__ bias_exp,
    float* __restrict__ out)
{
    __shared__ __align__(16) char sm[SMEM_BYTES];
    const int tid  = threadIdx.x;
    const int w    = tid >> 6;       // wave = head
    const int lane = tid & 63;
    const int l15  = lane & 15;
    const int g    = lane >> 4;      // 16-lane group 0..3
    const int b    = blockIdx.x;

    const float* xb = x + (size_t)b * 16384;
    const float* yb = y + (size_t)b * 16384;

    // ---------------- P0: stage x,y as f16 (padded rows) ----------------
    #pragma unroll
    for (int it = 0; it < 4; ++it) {
        int c = tid + it * 512;          // 2048 chunks of 8 f32
        int row = c >> 5, c8 = c & 31;
        float4 a0 = *(const float4*)(xb + row * 256 + c8 * 8);
        float4 a1 = *(const float4*)(xb + row * 256 + c8 * 8 + 4);
        float4 b0 = *(const float4*)(yb + row * 256 + c8 * 8);
        float4 b1 = *(const float4*)(yb + row * 256 + c8 * 8 + 4);
        half8 hx, hy;
        hx[0]=(half_t)a0.x; hx[1]=(half_t)a0.y; hx[2]=(half_t)a0.z; hx[3]=(half_t)a0.w;
        hx[4]=(half_t)a1.x; hx[5]=(half_t)a1.y; hx[6]=(half_t)a1.z; hx[7]=(half_t)a1.w;
        hy[0]=(half_t)b0.x; hy[1]=(half_t)b0.y; hy[2]=(half_t)b0.z; hy[3]=(half_t)b0.w;
        hy[4]=(half_t)b1.x; hy[5]=(half_t)b1.y; hy[6]=(half_t)b1.z; hy[7]=(half_t)b1.w;
        int off = row * ROWB + c8 * 16;
        *(half8*)(sm + S_X + off) = hx;
        *(half8*)(sm + S_Y + off) = hy;
    }
    __syncthreads();

    // ---------------- P1: Q = (x @ q_w^T + q_b) * scale -> sQ (f16 token-major)
    {
        const half_t* wq = w16;
        const int jf0 = w * 32;
        f32x4 acc[4][2];
        #pragma unroll
        for (int mt = 0; mt < 4; ++mt)
            #pragma unroll
            for (int nt = 0; nt < 2; ++nt) { f32x4 z = {0.f,0.f,0.f,0.f}; acc[mt][nt] = z; }
        #pragma unroll
        for (int kc = 0; kc < 8; ++kc) {
            int k0 = kc * 32 + g * 8;
            half8 a[4];
            #pragma unroll
            for (int mt = 0; mt < 4; ++mt)
                a[mt] = *(const half8*)(sm + S_X + (mt * 16 + l15) * ROWB + k0 * 2);
            half8 bf[2];
            #pragma unroll
            for (int nt = 0; nt < 2; ++nt)
                bf[nt] = *(const half8*)(wq + (jf0 + nt * 16 + l15) * 256 + k0);
            #pragma unroll
            for (int mt = 0; mt < 4; ++mt)
                #pragma unroll
                for (int nt = 0; nt < 2; ++nt)
                    acc[mt][nt] = __builtin_amdgcn_mfma_f32_16x16x32_f16(a[mt], bf[nt], acc[mt][nt], 0, 0, 0);
        }
        #pragma unroll
        for (int nt = 0; nt < 2; ++nt) {
            int jf = jf0 + nt * 16 + l15;
            float qb_ = q_b[jf];
            #pragma unroll
            for (int mt = 0; mt < 4; ++mt)
                #pragma unroll
                for (int r = 0; r < 4; ++r) {
                    int i = mt * 16 + g * 4 + r;
                    *(half_t*)(sm + S_Q + i * ROWB + jf * 2) = (half_t)((acc[mt][nt][r] + qb_) * SCALE);
                }
        }
    }
    __syncthreads();   // sX about to be overwritten by K

    // ---------------- P2: K,V = y @ kv_w^T + kv_b ; K->sX token-major, V->sVt feature-major
    {
        const half_t* wkv = w16 + 65536;
        const int jf0 = w * 32;
        f32x4 ak[4][2], av[4][2];
        #pragma unroll
        for (int mt = 0; mt < 4; ++mt)
            #pragma unroll
            for (int nt = 0; nt < 2; ++nt) {
                f32x4 z = {0.f,0.f,0.f,0.f}; ak[mt][nt] = z; av[mt][nt] = z;
            }
        #pragma unroll
        for (int kc = 0; kc < 8; ++kc) {
            int k0 = kc * 32 + g * 8;
            half8 a[4];
            #pragma unroll
            for (int mt = 0; mt < 4; ++mt)
                a[mt] = *(const half8*)(sm + S_Y + (mt * 16 + l15) * ROWB + k0 * 2);
            half8 bk[2], bv[2];
            #pragma unroll
            for (int nt = 0; nt < 2; ++nt) {
                int jf = jf0 + nt * 16 + l15;
                bk[nt] = *(const half8*)(wkv + jf * 256 + k0);
                bv[nt] = *(const half8*)(wkv + (256 + jf) * 256 + k0);
            }
            #pragma unroll
            for (int mt = 0; mt < 4; ++mt)
                #pragma unroll
                for (int nt = 0; nt < 2; ++nt) {
                    ak[mt][nt] = __builtin_amdgcn_mfma_f32_16x16x32_f16(a[mt], bk[nt], ak[mt][nt], 0, 0, 0);
                    av[mt][nt] = __builtin_amdgcn_mfma_f32_16x16x32_f16(a[mt], bv[nt], av[mt][nt], 0, 0, 0);
                }
        }
        #pragma unroll
        for (int nt = 0; nt < 2; ++nt) {
            int jf = jf0 + nt * 16 + l15;
            float kb = kv_b[jf];
            #pragma unroll
            for (int mt = 0; mt < 4; ++mt)
                #pragma unroll
                for (int r = 0; r < 4; ++r) {
                    int i = mt * 16 + g * 4 + r;
                    *(half_t*)(sm + S_X + i * ROWB + jf * 2) = (half_t)(ak[mt][nt][r] + kb);
                }
        }
        #pragma unroll
        for (int nt = 0; nt < 2; ++nt) {
            int jf = jf0 + nt * 16 + l15;
            float vb = kv_b[256 + jf];
            #pragma unroll
            for (int mt = 0; mt < 4; ++mt) {
                int i0 = mt * 16 + g * 4;
                half4v hv;
                hv[0] = (half_t)(av[mt][nt][0] + vb);
                hv[1] = (half_t)(av[mt][nt][1] + vb);
                hv[2] = (half_t)(av[mt][nt][2] + vb);
                hv[3] = (half_t)(av[mt][nt][3] + vb);
                *(half4v*)(sm + S_VT + jf * VROWB + i0 * 2) = hv;
            }
        }
    }
    __syncthreads();

    // ---------------- P3: attention, head h = wave ----------------
    {
        const int h = w;
        const float* mw = mask + (size_t)(b & 1023) * 4096;
        const float* be = bias_exp + h * 4096;
        const int k0 = h * 32 + g * 8;

        // S^T = K @ Q^T  (A = K_h rows=kv-token j ; B = Q_h^T cols=q-token i)
        half8 ka[4], qf[4];
        #pragma unroll
        for (int mt = 0; mt < 4; ++mt)
            ka[mt] = *(const half8*)(sm + S_X + (mt * 16 + l15) * ROWB + k0 * 2);
        #pragma unroll
        for (int nt = 0; nt < 4; ++nt)
            qf[nt] = *(const half8*)(sm + S_Q + (nt * 16 + l15) * ROWB + k0 * 2);
        f32x4 t[4][4];
        #pragma unroll
        for (int mt = 0; mt < 4; ++mt)
            #pragma unroll
            for (int nt = 0; nt < 4; ++nt) {
                f32x4 z = {0.f,0.f,0.f,0.f};
                t[mt][nt] = __builtin_amdgcn_mfma_f32_16x16x32_f16(ka[mt], qf[nt], z, 0, 0, 0);
            }

        // t[mt][nt][r]: j = mt*16+g*4+r (kv), i = nt*16+l15 (q). softmax over j.
        #pragma unroll
        for (int nt = 0; nt < 4; ++nt) {
            int i = nt * 16 + l15;
            #pragma unroll
            for (int mt = 0; mt < 4; ++mt) {
                int j0 = mt * 16 + g * 4;
                float4 mv = *(const float4*)(mw + i * 64 + j0);
                float4 bv = *(const float4*)(be + i * 64 + j0);
                t[mt][nt][0] += mv.x + bv.x;
                t[mt][nt][1] += mv.y + bv.y;
                t[mt][nt][2] += mv.z + bv.z;
                t[mt][nt][3] += mv.w + bv.w;
            }
            float m = -1e30f;
            #pragma unroll
            for (int mt = 0; mt < 4; ++mt)
                #pragma unroll
                for (int r = 0; r < 4; ++r) m = fmaxf(m, t[mt][nt][r]);
            m = fmaxf(m, __shfl_xor(m, 16));
            m = fmaxf(m, __shfl_xor(m, 32));
            float s = 0.f;
            #pragma unroll
            for (int mt = 0; mt < 4; ++mt)
                #pragma unroll
                for (int r = 0; r < 4; ++r) {
                    float p = __expf(t[mt][nt][r] - m);
                    t[mt][nt][r] = p;
                    s += p;
                }
            s += __shfl_xor(s, 16);
            s += __shfl_xor(s, 32);
            float inv = 1.f / s;
            #pragma unroll
            for (int mt = 0; mt < 4; ++mt)
                #pragma unroll
                for (int r = 0; r < 4; ++r) t[mt][nt][r] *= inv;
        }

        // write P row-major into dead Q_h / K_h columns (wave-private):
        // P[i][j]: j<32 -> sQ col h*32+j ; j>=32 -> sX col h*32+(j-32)
        #pragma unroll
        for (int nt = 0; nt < 4; ++nt) {
            int i = nt * 16 + l15;
            #pragma unroll
            for (int mt = 0; mt < 4; ++mt) {
                int jc = (mt & 1) * 16 + g * 4;
                int base = (mt < 2) ? S_Q : S_X;
                half4v pv;
                pv[0] = (half_t)t[mt][nt][0];
                pv[1] = (half_t)t[mt][nt][1];
                pv[2] = (half_t)t[mt][nt][2];
                pv[3] = (half_t)t[mt][nt][3];
                *(half4v*)(sm + base + i * ROWB + (h * 32 + jc) * 2) = pv;
            }
        }
        asm volatile("s_waitcnt lgkmcnt(0)" ::: "memory");

        // O^T = V^T @ P^T : A rows = feature d ; B cols = q-token i
        f32x4 o[2][4];
        #pragma unroll
        for (int dt = 0; dt < 2; ++dt)
            #pragma unroll
            for (int nt = 0; nt < 4; ++nt) { f32x4 z = {0.f,0.f,0.f,0.f}; o[dt][nt] = z; }
        #pragma unroll
        for (int kc = 0; kc < 2; ++kc) {
            int jb = g * 8;
            half8 va[2];
            #pragma unroll
            for (int dt = 0; dt < 2; ++dt) {
                int fr = h * 32 + dt * 16 + l15;
                va[dt] = *(const half8*)(sm + S_VT + fr * VROWB + (kc * 32 + jb) * 2);
            }
            int base = kc ? S_X : S_Q;
            half8 pf[4];
            #pragma unroll
            for (int nt = 0; nt < 4; ++nt)
                pf[nt] = *(const half8*)(sm + base + (nt * 16 + l15) * ROWB + (h * 32 + jb) * 2);
            #pragma unroll
            for (int dt = 0; dt < 2; ++dt)
                #pragma unroll
                for (int nt = 0; nt < 4; ++nt)
                    o[dt][nt] = __builtin_amdgcn_mfma_f32_16x16x32_f16(va[dt], pf[nt], o[dt][nt], 0, 0, 0);
        }
        // O[i][h*32+d] -> sQ (token-major) for final projection
        #pragma unroll
        for (int nt = 0; nt < 4; ++nt) {
            int i = nt * 16 + l15;
            #pragma unroll
            for (int dt = 0; dt < 2; ++dt) {
                int d0 = dt * 16 + g * 4;
                half4v ov;
                ov[0] = (half_t)o[dt][nt][0];
                ov[1] = (half_t)o[dt][nt][1];
                ov[2] = (half_t)o[dt][nt][2];
                ov[3] = (half_t)o[dt][nt][3];
                *(half4v*)(sm + S_Q + i * ROWB + (h * 32 + d0) * 2) = ov;
            }
        }
    }
    __syncthreads();

    // ---------------- P4: out = O @ proj_w^T + proj_b (f32 global) ----------------
    {
        const half_t* wp = w16 + 196608;
        const int jf0 = w * 32;
        f32x4 acc[4][2];
        #pragma unroll
        for (int mt = 0; mt < 4; ++mt)
            #pragma unroll
            for (int nt = 0; nt < 2; ++nt) { f32x4 z = {0.f,0.f,0.f,0.f}; acc[mt][nt] = z; }
        #pragma unroll
        for (int kc = 0; kc < 8; ++kc) {
            int k0 = kc * 32 + g * 8;
            half8 a[4];
            #pragma unroll
            for (int mt = 0; mt < 4; ++mt)
                a[mt] = *(const half8*)(sm + S_Q + (mt * 16 + l15) * ROWB + k0 * 2);
            half8 bf[2];
            #pragma unroll
            for (int nt = 0; nt < 2; ++nt)
                bf[nt] = *(const half8*)(wp + (jf0 + nt * 16 + l15) * 256 + k0);
            #pragma unroll
            for (int mt = 0; mt < 4; ++mt)
                #pragma unroll
                for (int nt = 0; nt < 2; ++nt)
                    acc[mt][nt] = __builtin_amdgcn_mfma_f32_16x16x32_f16(a[mt], bf[nt], acc[mt][nt], 0, 0, 0);
        }
        float* ob = out + (size_t)b * 16384;
        #pragma unroll
        for (int nt = 0; nt < 2; ++nt) {
            int jf = jf0 + nt * 16 + l15;
            float pbv = proj_b[jf];
            #pragma unroll
            for (int mt = 0; mt < 4; ++mt)
                #pragma unroll
                for (int r = 0; r < 4; ++r) {
                    int i = mt * 16 + g * 4 + r;
                    ob[i * 256 + jf] = acc[mt][nt][r] + pbv;
                }
        }
    }
}

extern "C" void kernel_launch(void* const* d_in, const int* in_sizes, int n_in,
                              void* d_out, int out_size, void* d_ws, size_t ws_size,
                              hipStream_t stream) {
    const float* x      = (const float*)d_in[0];
    const float* y      = (const float*)d_in[1];
    const float* mask   = (const float*)d_in[2];
    const float* q_w    = (const float*)d_in[3];
    const float* q_b    = (const float*)d_in[4];
    const float* kv_w   = (const float*)d_in[5];
    const float* kv_b   = (const float*)d_in[6];
    const float* proj_w = (const float*)d_in[7];
    const float* proj_b = (const float*)d_in[8];
    const float* rpb    = (const float*)d_in[9];

    half_t* w16     = (half_t*)d_ws;                       // 262144 f16 = 512KB
    float* bias_exp = (float*)((char*)d_ws + 524288);      // 32768 f32 = 128KB

    swin_prep<<<1152, 256, 0, stream>>>(q_w, kv_w, proj_w, rpb, w16, bias_exp);
    swin_main<<<4096, 512, 0, stream>>>(x, y, mask, q_b, kv_b, proj_b,
                                        w16, bias_exp, (float*)d_out);
}